// Round 7
// baseline (564.851 us; speedup 1.0000x reference)
//
#include <hip/hip_runtime.h>

#define TSZ 32768
#define LWN 98304

typedef float f32x4 __attribute__((ext_vector_type(4)));
typedef float f32x8 __attribute__((ext_vector_type(8)));
typedef short s16x8 __attribute__((ext_vector_type(8)));
typedef unsigned short u16x8 __attribute__((ext_vector_type(8)));

__device__ __forceinline__ float leaky(float x) { return fmaxf(x, 0.2f * x); }
__device__ __forceinline__ float bf2f(unsigned short b) { return __uint_as_float(((unsigned)b) << 16); }
__device__ __forceinline__ unsigned short f2bf(float f) {
  unsigned u = __float_as_uint(f);
  u += 0x7fffu + ((u >> 16) & 1u);
  return (unsigned short)(u >> 16);
}

// truncation hi/lo split: hi = trunc-to-bf16(x), lo = trunc-to-bf16(x - hi).
__device__ __forceinline__ void split_trunc(float xv, short& hi, short& lo) {
  unsigned bits = __float_as_uint(xv);
  hi = (short)(bits >> 16);
  float hif = __uint_as_float(bits & 0xffff0000u);
  lo = (short)(__float_as_uint(xv - hif) >> 16);
}

// kb column permutation: P = l2*24576 + c*64 + i  <->  n = l2*24576 + i*384 + c
// (c = ocol*3 + kk, i = k_idx & 63). Makes lvc B-fragments 16B-contiguous.
__device__ __forceinline__ int perm_n_of_P(int P) {
  int l2 = P / 24576;
  int r = P - l2 * 24576;
  int c = r >> 6, i = r & 63;
  return l2 * 24576 + i * 384 + c;
}

// ---------------- ct weights -> hi/lo B-fragment pairs (per phase) ----------------
__global__ __launch_bounds__(256) void ctwfrag_kernel(const float* __restrict__ ct_w,
                                                      unsigned short* __restrict__ ctwf) {
  int ft = blockIdx.x * 256 + threadIdx.x;  // 8192
  int lane = ft & 63, frag = ft >> 6;       // 128 frags
  int phi = frag >> 4, fr = frag & 15;
  int nt = fr >> 2, kf = fr & 3;
  int w0 = (11 - phi) & 7;
  int o = nt * 16 + (lane & 15);
  int k0 = kf * 32 + (lane >> 4) * 8;
  u16x8 vh, vl;
  for (int j = 0; j < 8; j++) {
    int k = k0 + j, w2 = k >> 6, i = k & 63;
    float wv = ct_w[(w0 + 8 * w2) * 4096 + i * 64 + o];
    unsigned short hi = f2bf(wv);
    vh[j] = hi;
    vl[j] = f2bf(wv - bf2f(hi));
  }
  *(u16x8*)(ctwf + ((size_t)frag * 64 + lane) * 8) = vh;
  *(u16x8*)(ctwf + ((size_t)(frag + 128) * 64 + lane) * 8) = vl;
}

// ---------------- conv_transpose as MFMA GEMM (per phase): M=4096/b, N=64, K=128 ---
__global__ __launch_bounds__(256) void ctm_kernel(const float* __restrict__ x,
                                                  const unsigned short* __restrict__ ctwf,
                                                  const float* __restrict__ ct_b,
                                                  float* __restrict__ h) {
  int tid = threadIdx.x;
  int w = tid >> 6, lane = tid & 63;
  int col = lane & 15, q = lane >> 4;
  int bid = blockIdx.x;  // 512
  int blk = bid & 15, phi = (bid >> 4) & 7, b = bid >> 7;
  int w0 = (11 - phi) & 7;
  int d0 = (phi + w0 - 11) >> 3;  // -1 or 0
  int mm0 = blk * 256 + w * 64;
  const float* xb = x + (((size_t)b) << 12) * 64;
  const s16x8* wf = (const s16x8*)ctwf;

  f32x4 acc[4][4];
  for (int mt = 0; mt < 4; mt++)
    for (int cg = 0; cg < 4; cg++) acc[mt][cg] = (f32x4){0.f, 0.f, 0.f, 0.f};

#pragma unroll
  for (int kf = 0; kf < 4; kf++) {
    s16x8 bh[4], bl[4];
#pragma unroll
    for (int cg = 0; cg < 4; cg++) {
      int frag = (phi * 4 + cg) * 4 + kf;
      bh[cg] = wf[frag * 64 + lane];
      bl[cg] = wf[(frag + 128) * 64 + lane];
    }
    int k0 = kf * 32 + q * 8;
    int w2 = k0 >> 6, i0 = k0 & 63;
    int rb = mm0 + d0 + w2;
    s16x8 ah[4], al[4];
#pragma unroll
    for (int mt = 0; mt < 4; mt++) {
      int r = rb + mt * 16 + col;
      bool oob = ((unsigned)r >= 4096u);
      int rc = oob ? 0 : r;
      f32x8 v = *(const f32x8*)(xb + (size_t)rc * 64 + i0);
#pragma unroll
      for (int j = 0; j < 8; j++) {
        float xv = oob ? 0.f : leaky(v[j]);
        short hi, lo;
        split_trunc(xv, hi, lo);
        ah[mt][j] = hi;
        al[mt][j] = lo;
      }
    }
#pragma unroll
    for (int mt = 0; mt < 4; mt++)
#pragma unroll
      for (int cg = 0; cg < 4; cg++) {
        acc[mt][cg] = __builtin_amdgcn_mfma_f32_16x16x32_bf16(ah[mt], bh[cg], acc[mt][cg], 0, 0, 0);
        acc[mt][cg] = __builtin_amdgcn_mfma_f32_16x16x32_bf16(al[mt], bh[cg], acc[mt][cg], 0, 0, 0);
        acc[mt][cg] = __builtin_amdgcn_mfma_f32_16x16x32_bf16(ah[mt], bl[cg], acc[mt][cg], 0, 0, 0);
      }
  }

  float* hb = h + (((size_t)b) << 15) * 64;
#pragma unroll
  for (int cg = 0; cg < 4; cg++) {
    int o = cg * 16 + col;
    float bias = ct_b[o];
#pragma unroll
    for (int mt = 0; mt < 4; mt++)
#pragma unroll
      for (int r = 0; r < 4; r++) {
        int mm = mm0 + mt * 16 + q * 4 + r;
        int t = mm * 8 + phi;
        hb[(size_t)t * 64 + o] = acc[mt][cg][r] + bias;
      }
  }
}

// ---------------- conditioning network (tiny) -----------------
__global__ __launch_bounds__(256) void conv5_kernel(const float* __restrict__ c,
                                                    const float* __restrict__ w,
                                                    const float* __restrict__ bias,
                                                    float* __restrict__ cc) {
  int f = blockIdx.x * 256 + threadIdx.x;  // 32768
  int o = f & 63, t = (f >> 6) & 127, b = f >> 13;
  float acc = bias[o];
  for (int kk = 0; kk < 5; kk++) {
    int tt = t + kk - 2;
    if (tt < 0 || tt >= 128) continue;
    const float* cr = c + (b * 128 + tt) * 80;
    const float* wr = w + kk * 80 * 64 + o;
    for (int i = 0; i < 80; i++) acc += cr[i] * wr[i * 64];
  }
  cc[f] = leaky(acc);
}

template <int ADD>
__global__ __launch_bounds__(256) void conv3_kernel(const float* __restrict__ xin,
                                                    const float* __restrict__ w,
                                                    const float* __restrict__ bias,
                                                    const float* __restrict__ addsrc,
                                                    float* __restrict__ out) {
  int f = blockIdx.x * 256 + threadIdx.x;  // 32768
  int o = f & 63, t = (f >> 6) & 127, b = f >> 13;
  float acc = bias[o];
  for (int kk = 0; kk < 3; kk++) {
    int tt = t + kk - 1;
    if (tt < 0 || tt >= 128) continue;
    const float* xr = xin + (b * 128 + tt) * 64;
    const float* wr = w + kk * 64 * 64 + o;
    for (int i = 0; i < 64; i++) acc += xr[i] * wr[i * 64];
  }
  float v = leaky(acc);
  if (ADD) v += addsrc[f];
  out[f] = v;
}

// ---------------- im2col patches for the prediction GEMMs -----------------
__global__ __launch_bounds__(256) void patch_kernel(const float* __restrict__ cc,
                                                    float* __restrict__ A) {
  int f = blockIdx.x * 256 + threadIdx.x;  // 98304
  int k = f % 192, m = f / 192;
  int b = m >> 7, l = m & 127;
  int kk = k >> 6, hh = k & 63;
  int ll = l + kk - 1;
  A[f] = (ll >= 0 && ll < 128) ? cc[((b << 7) + ll) * 64 + hh] : 0.f;
}

__global__ __launch_bounds__(256) void bbgemm_kernel(const float* __restrict__ A,
                                                     const float* __restrict__ w,
                                                     const float* __restrict__ bias,
                                                     float* __restrict__ bb) {
  int f = blockIdx.x * 256 + threadIdx.x;  // 262144
  int n = f & 511, m = f >> 9;
  float acc = bias[n];
  const float* ar = A + m * 192;
  const float* wr = w + n;
  for (int k = 0; k < 192; k++) acc += ar[k] * wr[k * 512];
  bb[f] = acc;
}

// ---------------- pre-swizzle W into MFMA fragment layout, P-ordered columns ------
__global__ __launch_bounds__(256) void wreorg_kernel(const float* __restrict__ W,
                                                     unsigned short* __restrict__ Wf) {
  int ft = blockIdx.x * 256 + threadIdx.x;  // 2359296
  int lane = ft & 63, fragid = ft >> 6;
  int kf = fragid % 6, nt = fragid / 6;
  int col = lane & 15, q = lane >> 4;
  int n = perm_n_of_P(nt * 16 + col);
  u16x8 v;
  for (int j = 0; j < 8; j++) {
    int kki = kf * 32 + q * 8 + j;
    v[j] = f2bf(W[(size_t)kki * LWN + n]);
  }
  *(u16x8*)(Wf + ((size_t)fragid * 64 + lane) * 8) = v;
}

__global__ __launch_bounds__(256) void afrag_kernel(const float* __restrict__ A,
                                                    unsigned short* __restrict__ Af) {
  int ft = blockIdx.x * 256 + threadIdx.x;  // 12288
  int lane = ft & 63, fragid = ft >> 6;
  int kf = fragid % 6, mt = fragid / 6;
  int row = lane & 15, q = lane >> 4;
  const float* ar = A + (mt * 16 + row) * 192 + kf * 32 + q * 8;
  u16x8 v;
  for (int j = 0; j < 8; j++) v[j] = f2bf(ar[j]);
  *(u16x8*)(Af + ((size_t)fragid * 64 + lane) * 8) = v;
}

// ---------------- dconv weights -> B-fragment layout (all 4 layers, built once) ----
__global__ __launch_bounds__(256) void dwfrag_kernel(const float* __restrict__ conv_w,
                                                     unsigned short* __restrict__ dwf) {
  int ft = blockIdx.x * 256 + threadIdx.x;  // 6144
  int lane = ft & 63, frag = ft >> 6;       // 96 frags
  int lay = frag / 24, fr = frag % 24;
  int nt = fr / 6, kf = fr % 6;
  int o = nt * 16 + (lane & 15);
  int k0 = kf * 32 + (lane >> 4) * 8;
  u16x8 v;
  for (int j = 0; j < 8; j++) {
    int k = k0 + j, kk = k >> 6, i = k & 63;
    v[j] = f2bf(conv_w[lay * 12288 + kk * 4096 + i * 64 + o]);
  }
  *(u16x8*)(dwf + ((size_t)frag * 64 + lane) * 8) = v;
}

// ---------------- k = A @ W + kern_b, output C[m][P] (P-permuted columns) ----------
__global__ __launch_bounds__(256) void kgemm_kernel(const unsigned short* __restrict__ Af,
                                                    const unsigned short* __restrict__ Wf,
                                                    const float* __restrict__ kern_b,
                                                    unsigned short* __restrict__ kbs) {
  __shared__ unsigned short cl[256 * 68];
  int tid = threadIdx.x;
  int wave = tid >> 6, lane = tid & 63;
  int col = lane & 15, q = lane >> 4;
  int mt0 = blockIdx.y * 16 + wave * 4;
  int nt0 = blockIdx.x * 4;
  f32x4 acc[4][4];
  for (int a = 0; a < 4; a++)
    for (int cg = 0; cg < 4; cg++) acc[a][cg] = (f32x4){0.f, 0.f, 0.f, 0.f};
  const s16x8* ap = (const s16x8*)Af;
  const s16x8* bp = (const s16x8*)Wf;
  for (int kf = 0; kf < 6; kf++) {
    s16x8 av[4], bv[4];
    for (int a = 0; a < 4; a++) av[a] = ap[((mt0 + a) * 6 + kf) * 64 + lane];
    for (int cg = 0; cg < 4; cg++) bv[cg] = bp[((size_t)(nt0 + cg) * 6 + kf) * 64 + lane];
    for (int a = 0; a < 4; a++)
      for (int cg = 0; cg < 4; cg++)
        acc[a][cg] = __builtin_amdgcn_mfma_f32_16x16x32_bf16(av[a], bv[cg], acc[a][cg], 0, 0, 0);
  }
  for (int cg = 0; cg < 4; cg++) {
    float bias = kern_b[perm_n_of_P((nt0 + cg) * 16 + col)];
    for (int a = 0; a < 4; a++) {
      int lr0 = wave * 64 + a * 16 + q * 4;
      for (int r = 0; r < 4; r++)
        cl[(lr0 + r) * 68 + cg * 16 + col] = f2bf(acc[a][cg][r] + bias);
    }
  }
  __syncthreads();
  size_t mbase = (size_t)blockIdx.y * 256;
  int nbase = blockIdx.x * 64;
#pragma unroll
  for (int rep = 0; rep < 8; rep++) {
    int cid = rep * 256 + tid;
    int row = cid >> 3, ch = cid & 7;
    u16x8 vv = *(const u16x8*)(cl + row * 68 + ch * 8);
    *(u16x8*)(kbs + (mbase + row) * LWN + nbase + ch * 8) = vv;
  }
}

// ---------------- dilated conv as MFMA GEMM: M=131072, N=64, K=192 ----------------
__global__ __launch_bounds__(256) void dconv_kernel(const float* __restrict__ h,
                                                    const unsigned short* __restrict__ dwf,
                                                    const float* __restrict__ conv_b,
                                                    unsigned short* __restrict__ xc,
                                                    int lay, int d) {
  int tid = threadIdx.x;
  int w = tid >> 6, lane = tid & 63;
  int col = lane & 15, q = lane >> 4;
  int m0 = blockIdx.x * 256 + w * 64;
  int b = m0 >> 15, t0 = m0 & 32767;
  const float* hb = h + (((size_t)b) << 15) * 64;
  const s16x8* wf = (const s16x8*)(dwf + (size_t)lay * 24 * 512);

  f32x4 acc[4][4];
  for (int mt = 0; mt < 4; mt++)
    for (int cg = 0; cg < 4; cg++) acc[mt][cg] = (f32x4){0.f, 0.f, 0.f, 0.f};

#pragma unroll
  for (int kf = 0; kf < 6; kf++) {
    s16x8 bv[4];
#pragma unroll
    for (int cg = 0; cg < 4; cg++) bv[cg] = wf[(cg * 6 + kf) * 64 + lane];
    int k0 = kf * 32 + q * 8;
    int kk = k0 >> 6, i0 = k0 & 63;
    int dt = (kk - 1) * d;
    s16x8 ah[4], al[4];
#pragma unroll
    for (int mt = 0; mt < 4; mt++) {
      int t = t0 + mt * 16 + col + dt;
      bool oob = ((unsigned)t >= (unsigned)TSZ);
      int tc = oob ? 0 : t;
      f32x8 v = *(const f32x8*)(hb + (size_t)tc * 64 + i0);
#pragma unroll
      for (int j = 0; j < 8; j++) {
        float xv = oob ? 0.f : leaky(v[j]);
        short hi, lo;
        split_trunc(xv, hi, lo);
        ah[mt][j] = hi;
        al[mt][j] = lo;
      }
    }
#pragma unroll
    for (int mt = 0; mt < 4; mt++)
#pragma unroll
      for (int cg = 0; cg < 4; cg++) {
        acc[mt][cg] = __builtin_amdgcn_mfma_f32_16x16x32_bf16(ah[mt], bv[cg], acc[mt][cg], 0, 0, 0);
        acc[mt][cg] = __builtin_amdgcn_mfma_f32_16x16x32_bf16(al[mt], bv[cg], acc[mt][cg], 0, 0, 0);
      }
  }

  unsigned short* xb = xc + (((size_t)b) << 15) * 64;
#pragma unroll
  for (int cg = 0; cg < 4; cg++) {
    int o = cg * 16 + col;
    float bias = conv_b[lay * 64 + o];
#pragma unroll
    for (int mt = 0; mt < 4; mt++)
#pragma unroll
      for (int r = 0; r < 4; r++) {
        int t = t0 + mt * 16 + q * 4 + r;
        xb[(size_t)t * 64 + o] = f2bf(leaky(acc[mt][cg][r] + bias));
      }
  }
}

// ---------------- LVC as per-(b,l) MFMA GEMM: M=256, N=128, K=192 ----------------
// B-frags now 16B-contiguous in the P-permuted kb: addr = srow + (o*3+kk)*64 + i0.
__global__ __launch_bounds__(512) void lvc_kernel(const unsigned short* __restrict__ xc,
                                                  const unsigned short* __restrict__ kbs,
                                                  const float* __restrict__ bbv,
                                                  float* __restrict__ h, int lay) {
  int tid = threadIdx.x;
  int l = blockIdx.x & 127, b = blockIdx.x >> 7;
  int w = tid >> 6, lane = tid & 63;
  int wm = w & 3, wn = w >> 2;
  int col = lane & 15, qq = lane >> 4;
  const unsigned short* srow =
      kbs + (size_t)(b * 128 + lay * 32 + (l >> 2)) * LWN + (l & 3) * 24576;
  const unsigned short* xb = xc + (((size_t)b) << 15) * 64;

  f32x4 acc[4][4];
  for (int mt = 0; mt < 4; mt++)
    for (int cg = 0; cg < 4; cg++) acc[mt][cg] = (f32x4){0.f, 0.f, 0.f, 0.f};

  s16x8 av[2][4], bv[2][4];
  const s16x8 zfrag = {0, 0, 0, 0, 0, 0, 0, 0};

#define LOAD_STEP(p, kf)                                                            \
  {                                                                                 \
    int k0 = (kf) * 32 + qq * 8;                                                    \
    int kk = k0 >> 6, i0 = k0 & 63;                                                 \
    _Pragma("unroll") for (int mt = 0; mt < 4; mt++) {                              \
      int s = wm * 64 + mt * 16 + col;                                              \
      int nr = 3 * s + kk - 255;                                                    \
      int n = nr < 0 ? -nr : (nr >= 258 ? 514 - nr : nr);                           \
      int t = l * 256 + n - 1;                                                      \
      bool oob = ((unsigned)t >= (unsigned)TSZ);                                    \
      int tc = oob ? 0 : t;                                                         \
      s16x8 v = *(const s16x8*)(xb + (size_t)tc * 64 + i0);                         \
      av[p][mt] = oob ? zfrag : v;                                                  \
    }                                                                               \
    _Pragma("unroll") for (int cg = 0; cg < 4; cg++) {                              \
      int nt = 2 * wn + (cg & 1) + ((cg >> 1) << 2);                                \
      int o = nt * 16 + col;                                                        \
      bv[p][cg] = *(const s16x8*)(srow + (o * 3 + kk) * 64 + i0);                   \
    }                                                                               \
  }

  LOAD_STEP(0, 0)
#pragma unroll
  for (int kf = 0; kf < 6; kf++) {
    int cur = kf & 1, nxt = cur ^ 1;
    if (kf < 5) LOAD_STEP(nxt, kf + 1)
#pragma unroll
    for (int mt = 0; mt < 4; mt++)
#pragma unroll
      for (int cg = 0; cg < 4; cg++)
        acc[mt][cg] =
            __builtin_amdgcn_mfma_f32_16x16x32_bf16(av[cur][mt], bv[cur][cg], acc[mt][cg], 0, 0, 0);
  }
#undef LOAD_STEP

  // epilogue: bias + sigmoid*tanh gate + h residual update
  int lq = l >> 2, l2 = l & 3;
  const float* bb0 = bbv + (size_t)(b * 128 + lay * 32 + lq) * 512 + l2 * 128;
  float* hb = h + ((((size_t)b) << 15) + l * 256) * 64;
#pragma unroll
  for (int mt = 0; mt < 4; mt++) {
#pragma unroll
    for (int p = 0; p < 2; p++) {
      int o = (2 * wn + p) * 16 + col;
      float b0 = bb0[o], b1 = bb0[o + 64];
#pragma unroll
      for (int r = 0; r < 4; r++) {
        int s = wm * 64 + mt * 16 + qq * 4 + r;
        float a0 = acc[mt][p][r] + b0;
        float a1 = acc[mt][p + 2][r] + b1;
        float sg = 1.f / (1.f + __expf(-a0));
        float ex = __expf(2.f * a1);
        float th = 1.f - 2.f / (ex + 1.f);
        hb[(size_t)s * 64 + o] += sg * th;
      }
    }
  }
}

extern "C" void kernel_launch(void* const* d_in, const int* in_sizes, int n_in,
                              void* d_out, int out_size, void* d_ws, size_t ws_size,
                              hipStream_t stream) {
  (void)in_sizes; (void)n_in; (void)out_size; (void)ws_size;
  const float* x      = (const float*)d_in[0];
  const float* c      = (const float*)d_in[1];
  const float* ct_w   = (const float*)d_in[2];
  const float* ct_b   = (const float*)d_in[3];
  const float* conv_w = (const float*)d_in[4];
  const float* conv_b = (const float*)d_in[5];
  const float* inp_w  = (const float*)d_in[6];
  const float* inp_b  = (const float*)d_in[7];
  const float* res_w1 = (const float*)d_in[8];
  const float* res_b1 = (const float*)d_in[9];
  const float* res_w2 = (const float*)d_in[10];
  const float* res_b2 = (const float*)d_in[11];
  const float* kern_w = (const float*)d_in[12];
  const float* kern_b = (const float*)d_in[13];
  const float* bias_w = (const float*)d_in[14];
  const float* bias_b = (const float*)d_in[15];

  float* h = (float*)d_out;  // h lives in d_out (fully written by ctm_kernel)
  char* ws = (char*)d_ws;
  // region [0, 37748736): Wf during GEMM phase, then reused as bf16 xc in layer phase
  unsigned short* Wf = (unsigned short*)(ws);
  unsigned short* xc = (unsigned short*)(ws);
  unsigned short* kb = (unsigned short*)(ws + 37748736);   // 100663296 B ([m][P] bf16)
  float* A           = (float*)(ws + 138412032);           // 393216 B
  unsigned short* Af = (unsigned short*)(ws + 138805248);  // 196608 B
  float* cc          = (float*)(ws + 139001856);           // 131072 B
  float* t1          = (float*)(ws + 139132928);           // 131072 B
  float* bbv         = (float*)(ws + 139264000);           // 1048576 B
  unsigned short* dwf = (unsigned short*)(ws + 140312576); // 98304 B
  // ctwf (262144 B) overlaps A/Af region: dead before patch_kernel writes A.
  unsigned short* ctwf = (unsigned short*)(ws + 138412032);

  ctwfrag_kernel<<<dim3(32), dim3(256), 0, stream>>>(ct_w, ctwf);
  ctm_kernel<<<dim3(512), dim3(256), 0, stream>>>(x, ctwf, ct_b, h);
  conv5_kernel<<<dim3(128), dim3(256), 0, stream>>>(c, inp_w, inp_b, cc);
  for (int j = 0; j < 3; j++) {
    conv3_kernel<0><<<dim3(128), dim3(256), 0, stream>>>(cc, res_w1 + j * 12288, res_b1 + j * 64,
                                                         (const float*)nullptr, t1);
    conv3_kernel<1><<<dim3(128), dim3(256), 0, stream>>>(t1, res_w2 + j * 12288, res_b2 + j * 64,
                                                         cc, cc);
  }
  patch_kernel<<<dim3(384), dim3(256), 0, stream>>>(cc, A);
  bbgemm_kernel<<<dim3(1024), dim3(256), 0, stream>>>(A, bias_w, bias_b, bbv);
  wreorg_kernel<<<dim3(9216), dim3(256), 0, stream>>>(kern_w, Wf);
  afrag_kernel<<<dim3(48), dim3(256), 0, stream>>>(A, Af);
  kgemm_kernel<<<dim3(1536, 2), dim3(256), 0, stream>>>(Af, Wf, kern_b, kb);
  dwfrag_kernel<<<dim3(24), dim3(256), 0, stream>>>(conv_w, dwf);

  const int dil[4] = {1, 3, 9, 27};
  for (int lay = 0; lay < 4; lay++) {
    dconv_kernel<<<dim3(512), dim3(256), 0, stream>>>(h, dwf, conv_b, xc, lay, dil[lay]);
    lvc_kernel<<<dim3(512), dim3(512), 0, stream>>>(xc, kb, bbv, h, lay);
  }
}

// Round 8
// 527.340 us; speedup vs baseline: 1.0711x; 1.0711x over previous
//
#include <hip/hip_runtime.h>

#define TSZ 32768
#define LWN 98304

typedef float f32x4 __attribute__((ext_vector_type(4)));
typedef float f32x8 __attribute__((ext_vector_type(8)));
typedef short s16x8 __attribute__((ext_vector_type(8)));
typedef unsigned short u16x8 __attribute__((ext_vector_type(8)));

__device__ __forceinline__ float leaky(float x) { return fmaxf(x, 0.2f * x); }
__device__ __forceinline__ float bf2f(unsigned short b) { return __uint_as_float(((unsigned)b) << 16); }
__device__ __forceinline__ unsigned short f2bf(float f) {
  unsigned u = __float_as_uint(f);
  u += 0x7fffu + ((u >> 16) & 1u);
  return (unsigned short)(u >> 16);
}

// truncation hi/lo split: hi = trunc-to-bf16(x), lo = trunc-to-bf16(x - hi).
__device__ __forceinline__ void split_trunc(float xv, short& hi, short& lo) {
  unsigned bits = __float_as_uint(xv);
  hi = (short)(bits >> 16);
  float hif = __uint_as_float(bits & 0xffff0000u);
  lo = (short)(__float_as_uint(xv - hif) >> 16);
}

// kb column permutation: P = l2*24576 + c*64 + i  <->  n = l2*24576 + i*384 + c
// (c = ocol*3 + kk, i = k_idx & 63). Makes lvc B-fragments 16B-contiguous.
__device__ __forceinline__ int perm_n_of_P(int P) {
  int l2 = P / 24576;
  int r = P - l2 * 24576;
  int c = r >> 6, i = r & 63;
  return l2 * 24576 + i * 384 + c;
}

// ---------------- ct weights -> hi/lo B-fragment pairs (per phase) ----------------
__global__ __launch_bounds__(256) void ctwfrag_kernel(const float* __restrict__ ct_w,
                                                      unsigned short* __restrict__ ctwf) {
  int ft = blockIdx.x * 256 + threadIdx.x;  // 8192
  int lane = ft & 63, frag = ft >> 6;       // 128 frags
  int phi = frag >> 4, fr = frag & 15;
  int nt = fr >> 2, kf = fr & 3;
  int w0 = (11 - phi) & 7;
  int o = nt * 16 + (lane & 15);
  int k0 = kf * 32 + (lane >> 4) * 8;
  u16x8 vh, vl;
  for (int j = 0; j < 8; j++) {
    int k = k0 + j, w2 = k >> 6, i = k & 63;
    float wv = ct_w[(w0 + 8 * w2) * 4096 + i * 64 + o];
    unsigned short hi = f2bf(wv);
    vh[j] = hi;
    vl[j] = f2bf(wv - bf2f(hi));
  }
  *(u16x8*)(ctwf + ((size_t)frag * 64 + lane) * 8) = vh;
  *(u16x8*)(ctwf + ((size_t)(frag + 128) * 64 + lane) * 8) = vl;
}

// ---------------- conv_transpose as MFMA GEMM (per phase): M=4096/b, N=64, K=128 ---
__global__ __launch_bounds__(256) void ctm_kernel(const float* __restrict__ x,
                                                  const unsigned short* __restrict__ ctwf,
                                                  const float* __restrict__ ct_b,
                                                  float* __restrict__ h) {
  int tid = threadIdx.x;
  int w = tid >> 6, lane = tid & 63;
  int col = lane & 15, q = lane >> 4;
  int bid = blockIdx.x;  // 512
  int blk = bid & 15, phi = (bid >> 4) & 7, b = bid >> 7;
  int w0 = (11 - phi) & 7;
  int d0 = (phi + w0 - 11) >> 3;  // -1 or 0
  int mm0 = blk * 256 + w * 64;
  const float* xb = x + (((size_t)b) << 12) * 64;
  const s16x8* wf = (const s16x8*)ctwf;

  f32x4 acc[4][4];
  for (int mt = 0; mt < 4; mt++)
    for (int cg = 0; cg < 4; cg++) acc[mt][cg] = (f32x4){0.f, 0.f, 0.f, 0.f};

#pragma unroll
  for (int kf = 0; kf < 4; kf++) {
    s16x8 bh[4], bl[4];
#pragma unroll
    for (int cg = 0; cg < 4; cg++) {
      int frag = (phi * 4 + cg) * 4 + kf;
      bh[cg] = wf[frag * 64 + lane];
      bl[cg] = wf[(frag + 128) * 64 + lane];
    }
    int k0 = kf * 32 + q * 8;
    int w2 = k0 >> 6, i0 = k0 & 63;
    int rb = mm0 + d0 + w2;
    s16x8 ah[4], al[4];
#pragma unroll
    for (int mt = 0; mt < 4; mt++) {
      int r = rb + mt * 16 + col;
      bool oob = ((unsigned)r >= 4096u);
      int rc = oob ? 0 : r;
      f32x8 v = *(const f32x8*)(xb + (size_t)rc * 64 + i0);
#pragma unroll
      for (int j = 0; j < 8; j++) {
        float xv = oob ? 0.f : leaky(v[j]);
        short hi, lo;
        split_trunc(xv, hi, lo);
        ah[mt][j] = hi;
        al[mt][j] = lo;
      }
    }
#pragma unroll
    for (int mt = 0; mt < 4; mt++)
#pragma unroll
      for (int cg = 0; cg < 4; cg++) {
        acc[mt][cg] = __builtin_amdgcn_mfma_f32_16x16x32_bf16(ah[mt], bh[cg], acc[mt][cg], 0, 0, 0);
        acc[mt][cg] = __builtin_amdgcn_mfma_f32_16x16x32_bf16(al[mt], bh[cg], acc[mt][cg], 0, 0, 0);
        acc[mt][cg] = __builtin_amdgcn_mfma_f32_16x16x32_bf16(ah[mt], bl[cg], acc[mt][cg], 0, 0, 0);
      }
  }

  float* hb = h + (((size_t)b) << 15) * 64;
#pragma unroll
  for (int cg = 0; cg < 4; cg++) {
    int o = cg * 16 + col;
    float bias = ct_b[o];
#pragma unroll
    for (int mt = 0; mt < 4; mt++)
#pragma unroll
      for (int r = 0; r < 4; r++) {
        int mm = mm0 + mt * 16 + q * 4 + r;
        int t = mm * 8 + phi;
        hb[(size_t)t * 64 + o] = acc[mt][cg][r] + bias;
      }
  }
}

// ---------------- conditioning network (tiny) -----------------
__global__ __launch_bounds__(256) void conv5_kernel(const float* __restrict__ c,
                                                    const float* __restrict__ w,
                                                    const float* __restrict__ bias,
                                                    float* __restrict__ cc) {
  int f = blockIdx.x * 256 + threadIdx.x;  // 32768
  int o = f & 63, t = (f >> 6) & 127, b = f >> 13;
  float acc = bias[o];
  for (int kk = 0; kk < 5; kk++) {
    int tt = t + kk - 2;
    if (tt < 0 || tt >= 128) continue;
    const float* cr = c + (b * 128 + tt) * 80;
    const float* wr = w + kk * 80 * 64 + o;
    for (int i = 0; i < 80; i++) acc += cr[i] * wr[i * 64];
  }
  cc[f] = leaky(acc);
}

template <int ADD>
__global__ __launch_bounds__(256) void conv3_kernel(const float* __restrict__ xin,
                                                    const float* __restrict__ w,
                                                    const float* __restrict__ bias,
                                                    const float* __restrict__ addsrc,
                                                    float* __restrict__ out) {
  int f = blockIdx.x * 256 + threadIdx.x;  // 32768
  int o = f & 63, t = (f >> 6) & 127, b = f >> 13;
  float acc = bias[o];
  for (int kk = 0; kk < 3; kk++) {
    int tt = t + kk - 1;
    if (tt < 0 || tt >= 128) continue;
    const float* xr = xin + (b * 128 + tt) * 64;
    const float* wr = w + kk * 64 * 64 + o;
    for (int i = 0; i < 64; i++) acc += xr[i] * wr[i * 64];
  }
  float v = leaky(acc);
  if (ADD) v += addsrc[f];
  out[f] = v;
}

// ---------------- im2col patches for the prediction GEMMs -----------------
__global__ __launch_bounds__(256) void patch_kernel(const float* __restrict__ cc,
                                                    float* __restrict__ A) {
  int f = blockIdx.x * 256 + threadIdx.x;  // 98304
  int k = f % 192, m = f / 192;
  int b = m >> 7, l = m & 127;
  int kk = k >> 6, hh = k & 63;
  int ll = l + kk - 1;
  A[f] = (ll >= 0 && ll < 128) ? cc[((b << 7) + ll) * 64 + hh] : 0.f;
}

__global__ __launch_bounds__(256) void bbgemm_kernel(const float* __restrict__ A,
                                                     const float* __restrict__ w,
                                                     const float* __restrict__ bias,
                                                     float* __restrict__ bb) {
  int f = blockIdx.x * 256 + threadIdx.x;  // 262144
  int n = f & 511, m = f >> 9;
  float acc = bias[n];
  const float* ar = A + m * 192;
  const float* wr = w + n;
  for (int k = 0; k < 192; k++) acc += ar[k] * wr[k * 512];
  bb[f] = acc;
}

// ---------------- W -> Wf (P-ordered fragment layout) via LDS-tiled transpose ------
// Block = (l2, kf, cb): c0 = cb*8. Stage W[32k x 64i x 8c] into LDS [kl][i][c]
// (32-B contiguous reads per lane; neighbor c-blocks complete the 128-B lines ->
// L2 dedups to ~one HBM pass of W). Then build the 32 complete fragments
// (nt = (l2*384+c)*4 + ih, this kf) from LDS and write 1-KB contiguous runs.
__global__ __launch_bounds__(256) void wfrag_kernel(const float* __restrict__ W,
                                                    unsigned short* __restrict__ Wf) {
  __shared__ unsigned short wl[32 * 64 * 8];  // 32 KB, [kl][i][c]
  int tid = threadIdx.x;
  int bid = blockIdx.x;  // 1152 = 48 cb * 6 kf * 4 l2
  int cb = bid % 48;
  int rest = bid / 48;
  int kf = rest % 6, l2 = rest / 6;
  int c0 = cb * 8;
  for (int it = 0; it < 8; it++) {
    int pair = it * 256 + tid;  // kl*64 + i
    int kl = pair >> 6, i = pair & 63;
    const float* src = W + (size_t)(kf * 32 + kl) * LWN + l2 * 24576 + i * 384 + c0;
    f32x4 a = *(const f32x4*)(src);
    f32x4 b2 = *(const f32x4*)(src + 4);
    u16x8 v;
    for (int j = 0; j < 4; j++) v[j] = f2bf(a[j]);
    for (int j = 0; j < 4; j++) v[4 + j] = f2bf(b2[j]);
    *(u16x8*)(wl + pair * 8) = v;
  }
  __syncthreads();
  for (int it = 0; it < 8; it++) {
    int slot = it * 256 + tid;  // f*64 + ln
    int f = slot >> 6, ln = slot & 63;
    int cl = f >> 2, ih = f & 3;
    int q = ln >> 4, col = ln & 15;
    int i = ih * 16 + col;
    u16x8 v;
#pragma unroll
    for (int j = 0; j < 8; j++) {
      int kl = q * 8 + j;
      v[j] = wl[(kl * 64 + i) * 8 + cl];
    }
    int nt = l2 * 1536 + (c0 + cl) * 4 + ih;
    *(u16x8*)(Wf + ((size_t)(nt * 6 + kf) * 64 + ln) * 8) = v;
  }
}

__global__ __launch_bounds__(256) void afrag_kernel(const float* __restrict__ A,
                                                    unsigned short* __restrict__ Af) {
  int ft = blockIdx.x * 256 + threadIdx.x;  // 12288
  int lane = ft & 63, fragid = ft >> 6;
  int kf = fragid % 6, mt = fragid / 6;
  int row = lane & 15, q = lane >> 4;
  const float* ar = A + (mt * 16 + row) * 192 + kf * 32 + q * 8;
  u16x8 v;
  for (int j = 0; j < 8; j++) v[j] = f2bf(ar[j]);
  *(u16x8*)(Af + ((size_t)fragid * 64 + lane) * 8) = v;
}

// ---------------- dconv weights -> B-fragment layout (all 4 layers, built once) ----
__global__ __launch_bounds__(256) void dwfrag_kernel(const float* __restrict__ conv_w,
                                                     unsigned short* __restrict__ dwf) {
  int ft = blockIdx.x * 256 + threadIdx.x;  // 6144
  int lane = ft & 63, frag = ft >> 6;       // 96 frags
  int lay = frag / 24, fr = frag % 24;
  int nt = fr / 6, kf = fr % 6;
  int o = nt * 16 + (lane & 15);
  int k0 = kf * 32 + (lane >> 4) * 8;
  u16x8 v;
  for (int j = 0; j < 8; j++) {
    int k = k0 + j, kk = k >> 6, i = k & 63;
    v[j] = f2bf(conv_w[lay * 12288 + kk * 4096 + i * 64 + o]);
  }
  *(u16x8*)(dwf + ((size_t)frag * 64 + lane) * 8) = v;
}

// ---------------- k = A @ W + kern_b, output C[m][P] (P-permuted columns) ----------
__global__ __launch_bounds__(256) void kgemm_kernel(const unsigned short* __restrict__ Af,
                                                    const unsigned short* __restrict__ Wf,
                                                    const float* __restrict__ kern_b,
                                                    unsigned short* __restrict__ kbs) {
  __shared__ unsigned short cl[256 * 68];
  int tid = threadIdx.x;
  int wave = tid >> 6, lane = tid & 63;
  int col = lane & 15, q = lane >> 4;
  int mt0 = blockIdx.y * 16 + wave * 4;
  int nt0 = blockIdx.x * 4;
  f32x4 acc[4][4];
  for (int a = 0; a < 4; a++)
    for (int cg = 0; cg < 4; cg++) acc[a][cg] = (f32x4){0.f, 0.f, 0.f, 0.f};
  const s16x8* ap = (const s16x8*)Af;
  const s16x8* bp = (const s16x8*)Wf;
  for (int kf = 0; kf < 6; kf++) {
    s16x8 av[4], bv[4];
    for (int a = 0; a < 4; a++) av[a] = ap[((mt0 + a) * 6 + kf) * 64 + lane];
    for (int cg = 0; cg < 4; cg++) bv[cg] = bp[((size_t)(nt0 + cg) * 6 + kf) * 64 + lane];
    for (int a = 0; a < 4; a++)
      for (int cg = 0; cg < 4; cg++)
        acc[a][cg] = __builtin_amdgcn_mfma_f32_16x16x32_bf16(av[a], bv[cg], acc[a][cg], 0, 0, 0);
  }
  for (int cg = 0; cg < 4; cg++) {
    float bias = kern_b[perm_n_of_P((nt0 + cg) * 16 + col)];
    for (int a = 0; a < 4; a++) {
      int lr0 = wave * 64 + a * 16 + q * 4;
      for (int r = 0; r < 4; r++)
        cl[(lr0 + r) * 68 + cg * 16 + col] = f2bf(acc[a][cg][r] + bias);
    }
  }
  __syncthreads();
  size_t mbase = (size_t)blockIdx.y * 256;
  int nbase = blockIdx.x * 64;
#pragma unroll
  for (int rep = 0; rep < 8; rep++) {
    int cid = rep * 256 + tid;
    int row = cid >> 3, ch = cid & 7;
    u16x8 vv = *(const u16x8*)(cl + row * 68 + ch * 8);
    *(u16x8*)(kbs + (mbase + row) * LWN + nbase + ch * 8) = vv;
  }
}

// ---------------- dilated conv as MFMA GEMM: M=131072, N=64, K=192 ----------------
__global__ __launch_bounds__(256) void dconv_kernel(const float* __restrict__ h,
                                                    const unsigned short* __restrict__ dwf,
                                                    const float* __restrict__ conv_b,
                                                    unsigned short* __restrict__ xc,
                                                    int lay, int d) {
  int tid = threadIdx.x;
  int w = tid >> 6, lane = tid & 63;
  int col = lane & 15, q = lane >> 4;
  int m0 = blockIdx.x * 256 + w * 64;
  int b = m0 >> 15, t0 = m0 & 32767;
  const float* hb = h + (((size_t)b) << 15) * 64;
  const s16x8* wf = (const s16x8*)(dwf + (size_t)lay * 24 * 512);

  f32x4 acc[4][4];
  for (int mt = 0; mt < 4; mt++)
    for (int cg = 0; cg < 4; cg++) acc[mt][cg] = (f32x4){0.f, 0.f, 0.f, 0.f};

#pragma unroll
  for (int kf = 0; kf < 6; kf++) {
    s16x8 bv[4];
#pragma unroll
    for (int cg = 0; cg < 4; cg++) bv[cg] = wf[(cg * 6 + kf) * 64 + lane];
    int k0 = kf * 32 + q * 8;
    int kk = k0 >> 6, i0 = k0 & 63;
    int dt = (kk - 1) * d;
    s16x8 ah[4], al[4];
#pragma unroll
    for (int mt = 0; mt < 4; mt++) {
      int t = t0 + mt * 16 + col + dt;
      bool oob = ((unsigned)t >= (unsigned)TSZ);
      int tc = oob ? 0 : t;
      f32x8 v = *(const f32x8*)(hb + (size_t)tc * 64 + i0);
#pragma unroll
      for (int j = 0; j < 8; j++) {
        float xv = oob ? 0.f : leaky(v[j]);
        short hi, lo;
        split_trunc(xv, hi, lo);
        ah[mt][j] = hi;
        al[mt][j] = lo;
      }
    }
#pragma unroll
    for (int mt = 0; mt < 4; mt++)
#pragma unroll
      for (int cg = 0; cg < 4; cg++) {
        acc[mt][cg] = __builtin_amdgcn_mfma_f32_16x16x32_bf16(ah[mt], bv[cg], acc[mt][cg], 0, 0, 0);
        acc[mt][cg] = __builtin_amdgcn_mfma_f32_16x16x32_bf16(al[mt], bv[cg], acc[mt][cg], 0, 0, 0);
      }
  }

  unsigned short* xb = xc + (((size_t)b) << 15) * 64;
#pragma unroll
  for (int cg = 0; cg < 4; cg++) {
    int o = cg * 16 + col;
    float bias = conv_b[lay * 64 + o];
#pragma unroll
    for (int mt = 0; mt < 4; mt++)
#pragma unroll
      for (int r = 0; r < 4; r++) {
        int t = t0 + mt * 16 + q * 4 + r;
        xb[(size_t)t * 64 + o] = f2bf(leaky(acc[mt][cg][r] + bias));
      }
  }
}

// ---------------- LVC as per-(b,l) MFMA GEMM: M=256, N=128, K=192 ----------------
// B-frags 16B-contiguous in the P-permuted kb: addr = srow + (o*3+kk)*64 + i0.
__global__ __launch_bounds__(512) void lvc_kernel(const unsigned short* __restrict__ xc,
                                                  const unsigned short* __restrict__ kbs,
                                                  const float* __restrict__ bbv,
                                                  float* __restrict__ h, int lay) {
  int tid = threadIdx.x;
  int l = blockIdx.x & 127, b = blockIdx.x >> 7;
  int w = tid >> 6, lane = tid & 63;
  int wm = w & 3, wn = w >> 2;
  int col = lane & 15, qq = lane >> 4;
  const unsigned short* srow =
      kbs + (size_t)(b * 128 + lay * 32 + (l >> 2)) * LWN + (l & 3) * 24576;
  const unsigned short* xb = xc + (((size_t)b) << 15) * 64;

  f32x4 acc[4][4];
  for (int mt = 0; mt < 4; mt++)
    for (int cg = 0; cg < 4; cg++) acc[mt][cg] = (f32x4){0.f, 0.f, 0.f, 0.f};

  s16x8 av[2][4], bv[2][4];
  const s16x8 zfrag = {0, 0, 0, 0, 0, 0, 0, 0};

#define LOAD_STEP(p, kf)                                                            \
  {                                                                                 \
    int k0 = (kf) * 32 + qq * 8;                                                    \
    int kk = k0 >> 6, i0 = k0 & 63;                                                 \
    _Pragma("unroll") for (int mt = 0; mt < 4; mt++) {                              \
      int s = wm * 64 + mt * 16 + col;                                              \
      int nr = 3 * s + kk - 255;                                                    \
      int n = nr < 0 ? -nr : (nr >= 258 ? 514 - nr : nr);                           \
      int t = l * 256 + n - 1;                                                      \
      bool oob = ((unsigned)t >= (unsigned)TSZ);                                    \
      int tc = oob ? 0 : t;                                                         \
      s16x8 v = *(const s16x8*)(xb + (size_t)tc * 64 + i0);                         \
      av[p][mt] = oob ? zfrag : v;                                                  \
    }                                                                               \
    _Pragma("unroll") for (int cg = 0; cg < 4; cg++) {                              \
      int nt = 2 * wn + (cg & 1) + ((cg >> 1) << 2);                                \
      int o = nt * 16 + col;                                                        \
      bv[p][cg] = *(const s16x8*)(srow + (o * 3 + kk) * 64 + i0);                   \
    }                                                                               \
  }

  LOAD_STEP(0, 0)
#pragma unroll
  for (int kf = 0; kf < 6; kf++) {
    int cur = kf & 1, nxt = cur ^ 1;
    if (kf < 5) LOAD_STEP(nxt, kf + 1)
#pragma unroll
    for (int mt = 0; mt < 4; mt++)
#pragma unroll
      for (int cg = 0; cg < 4; cg++)
        acc[mt][cg] =
            __builtin_amdgcn_mfma_f32_16x16x32_bf16(av[cur][mt], bv[cur][cg], acc[mt][cg], 0, 0, 0);
  }
#undef LOAD_STEP

  // epilogue: bias + sigmoid*tanh gate + h residual update
  int lq = l >> 2, l2 = l & 3;
  const float* bb0 = bbv + (size_t)(b * 128 + lay * 32 + lq) * 512 + l2 * 128;
  float* hb = h + ((((size_t)b) << 15) + l * 256) * 64;
#pragma unroll
  for (int mt = 0; mt < 4; mt++) {
#pragma unroll
    for (int p = 0; p < 2; p++) {
      int o = (2 * wn + p) * 16 + col;
      float b0 = bb0[o], b1 = bb0[o + 64];
#pragma unroll
      for (int r = 0; r < 4; r++) {
        int s = wm * 64 + mt * 16 + qq * 4 + r;
        float a0 = acc[mt][p][r] + b0;
        float a1 = acc[mt][p + 2][r] + b1;
        float sg = 1.f / (1.f + __expf(-a0));
        float ex = __expf(2.f * a1);
        float th = 1.f - 2.f / (ex + 1.f);
        hb[(size_t)s * 64 + o] += sg * th;
      }
    }
  }
}

extern "C" void kernel_launch(void* const* d_in, const int* in_sizes, int n_in,
                              void* d_out, int out_size, void* d_ws, size_t ws_size,
                              hipStream_t stream) {
  (void)in_sizes; (void)n_in; (void)out_size; (void)ws_size;
  const float* x      = (const float*)d_in[0];
  const float* c      = (const float*)d_in[1];
  const float* ct_w   = (const float*)d_in[2];
  const float* ct_b   = (const float*)d_in[3];
  const float* conv_w = (const float*)d_in[4];
  const float* conv_b = (const float*)d_in[5];
  const float* inp_w  = (const float*)d_in[6];
  const float* inp_b  = (const float*)d_in[7];
  const float* res_w1 = (const float*)d_in[8];
  const float* res_b1 = (const float*)d_in[9];
  const float* res_w2 = (const float*)d_in[10];
  const float* res_b2 = (const float*)d_in[11];
  const float* kern_w = (const float*)d_in[12];
  const float* kern_b = (const float*)d_in[13];
  const float* bias_w = (const float*)d_in[14];
  const float* bias_b = (const float*)d_in[15];

  float* h = (float*)d_out;  // h lives in d_out (fully written by ctm_kernel)
  char* ws = (char*)d_ws;
  // region [0, 37748736): Wf during GEMM phase, then reused as bf16 xc in layer phase
  unsigned short* Wf = (unsigned short*)(ws);
  unsigned short* xc = (unsigned short*)(ws);
  unsigned short* kb = (unsigned short*)(ws + 37748736);   // 100663296 B ([m][P] bf16)
  float* A           = (float*)(ws + 138412032);           // 393216 B
  unsigned short* Af = (unsigned short*)(ws + 138805248);  // 196608 B
  float* cc          = (float*)(ws + 139001856);           // 131072 B
  float* t1          = (float*)(ws + 139132928);           // 131072 B
  float* bbv         = (float*)(ws + 139264000);           // 1048576 B
  unsigned short* dwf = (unsigned short*)(ws + 140312576); // 98304 B
  // ctwf (262144 B) overlaps A/Af region: dead before patch_kernel writes A.
  unsigned short* ctwf = (unsigned short*)(ws + 138412032);

  ctwfrag_kernel<<<dim3(32), dim3(256), 0, stream>>>(ct_w, ctwf);
  ctm_kernel<<<dim3(512), dim3(256), 0, stream>>>(x, ctwf, ct_b, h);
  conv5_kernel<<<dim3(128), dim3(256), 0, stream>>>(c, inp_w, inp_b, cc);
  for (int j = 0; j < 3; j++) {
    conv3_kernel<0><<<dim3(128), dim3(256), 0, stream>>>(cc, res_w1 + j * 12288, res_b1 + j * 64,
                                                         (const float*)nullptr, t1);
    conv3_kernel<1><<<dim3(128), dim3(256), 0, stream>>>(t1, res_w2 + j * 12288, res_b2 + j * 64,
                                                         cc, cc);
  }
  patch_kernel<<<dim3(384), dim3(256), 0, stream>>>(cc, A);
  bbgemm_kernel<<<dim3(1024), dim3(256), 0, stream>>>(A, bias_w, bias_b, bbv);
  wfrag_kernel<<<dim3(1152), dim3(256), 0, stream>>>(kern_w, Wf);
  afrag_kernel<<<dim3(48), dim3(256), 0, stream>>>(A, Af);
  kgemm_kernel<<<dim3(1536, 2), dim3(256), 0, stream>>>(Af, Wf, kern_b, kb);
  dwfrag_kernel<<<dim3(24), dim3(256), 0, stream>>>(conv_w, dwf);

  const int dil[4] = {1, 3, 9, 27};
  for (int lay = 0; lay < 4; lay++) {
    dconv_kernel<<<dim3(512), dim3(256), 0, stream>>>(h, dwf, conv_b, xc, lay, dil[lay]);
    lvc_kernel<<<dim3(512), dim3(512), 0, stream>>>(xc, kb, bbv, h, lay);
  }
}

// Round 9
// 513.598 us; speedup vs baseline: 1.0998x; 1.0268x over previous
//
#include <hip/hip_runtime.h>

#define TSZ 32768
#define LWN 98304

typedef float f32x4 __attribute__((ext_vector_type(4)));
typedef float f32x8 __attribute__((ext_vector_type(8)));
typedef short s16x8 __attribute__((ext_vector_type(8)));
typedef unsigned short u16x8 __attribute__((ext_vector_type(8)));

__device__ __forceinline__ float leaky(float x) { return fmaxf(x, 0.2f * x); }
__device__ __forceinline__ float bf2f(unsigned short b) { return __uint_as_float(((unsigned)b) << 16); }
__device__ __forceinline__ unsigned short f2bf(float f) {
  unsigned u = __float_as_uint(f);
  u += 0x7fffu + ((u >> 16) & 1u);
  return (unsigned short)(u >> 16);
}

// truncation hi/lo split: hi = trunc-to-bf16(x), lo = trunc-to-bf16(x - hi).
__device__ __forceinline__ void split_trunc(float xv, short& hi, short& lo) {
  unsigned bits = __float_as_uint(xv);
  hi = (short)(bits >> 16);
  float hif = __uint_as_float(bits & 0xffff0000u);
  lo = (short)(__float_as_uint(xv - hif) >> 16);
}

// kb column permutation: P = l2*24576 + c*64 + i  <->  n = l2*24576 + i*384 + c
// (c = ocol*3 + kk, i = k_idx & 63). Makes lvc B-fragments 16B-contiguous.
__device__ __forceinline__ int perm_n_of_P(int P) {
  int l2 = P / 24576;
  int r = P - l2 * 24576;
  int c = r >> 6, i = r & 63;
  return l2 * 24576 + i * 384 + c;
}

// ---------------- ct weights -> hi/lo B-fragment pairs (per phase) ----------------
__global__ __launch_bounds__(256) void ctwfrag_kernel(const float* __restrict__ ct_w,
                                                      unsigned short* __restrict__ ctwf) {
  int ft = blockIdx.x * 256 + threadIdx.x;  // 8192
  int lane = ft & 63, frag = ft >> 6;       // 128 frags
  int phi = frag >> 4, fr = frag & 15;
  int nt = fr >> 2, kf = fr & 3;
  int w0 = (11 - phi) & 7;
  int o = nt * 16 + (lane & 15);
  int k0 = kf * 32 + (lane >> 4) * 8;
  u16x8 vh, vl;
  for (int j = 0; j < 8; j++) {
    int k = k0 + j, w2 = k >> 6, i = k & 63;
    float wv = ct_w[(w0 + 8 * w2) * 4096 + i * 64 + o];
    unsigned short hi = f2bf(wv);
    vh[j] = hi;
    vl[j] = f2bf(wv - bf2f(hi));
  }
  *(u16x8*)(ctwf + ((size_t)frag * 64 + lane) * 8) = vh;
  *(u16x8*)(ctwf + ((size_t)(frag + 128) * 64 + lane) * 8) = vl;
}

// ---------------- conv_transpose as MFMA GEMM (per phase): M=4096/b, N=64, K=128 ---
__global__ __launch_bounds__(256) void ctm_kernel(const float* __restrict__ x,
                                                  const unsigned short* __restrict__ ctwf,
                                                  const float* __restrict__ ct_b,
                                                  float* __restrict__ h) {
  int tid = threadIdx.x;
  int w = tid >> 6, lane = tid & 63;
  int col = lane & 15, q = lane >> 4;
  int bid = blockIdx.x;  // 512
  int blk = bid & 15, phi = (bid >> 4) & 7, b = bid >> 7;
  int w0 = (11 - phi) & 7;
  int d0 = (phi + w0 - 11) >> 3;  // -1 or 0
  int mm0 = blk * 256 + w * 64;
  const float* xb = x + (((size_t)b) << 12) * 64;
  const s16x8* wf = (const s16x8*)ctwf;

  f32x4 acc[4][4];
  for (int mt = 0; mt < 4; mt++)
    for (int cg = 0; cg < 4; cg++) acc[mt][cg] = (f32x4){0.f, 0.f, 0.f, 0.f};

#pragma unroll
  for (int kf = 0; kf < 4; kf++) {
    s16x8 bh[4], bl[4];
#pragma unroll
    for (int cg = 0; cg < 4; cg++) {
      int frag = (phi * 4 + cg) * 4 + kf;
      bh[cg] = wf[frag * 64 + lane];
      bl[cg] = wf[(frag + 128) * 64 + lane];
    }
    int k0 = kf * 32 + q * 8;
    int w2 = k0 >> 6, i0 = k0 & 63;
    int rb = mm0 + d0 + w2;
    s16x8 ah[4], al[4];
#pragma unroll
    for (int mt = 0; mt < 4; mt++) {
      int r = rb + mt * 16 + col;
      bool oob = ((unsigned)r >= 4096u);
      int rc = oob ? 0 : r;
      f32x8 v = *(const f32x8*)(xb + (size_t)rc * 64 + i0);
#pragma unroll
      for (int j = 0; j < 8; j++) {
        float xv = oob ? 0.f : leaky(v[j]);
        short hi, lo;
        split_trunc(xv, hi, lo);
        ah[mt][j] = hi;
        al[mt][j] = lo;
      }
    }
#pragma unroll
    for (int mt = 0; mt < 4; mt++)
#pragma unroll
      for (int cg = 0; cg < 4; cg++) {
        acc[mt][cg] = __builtin_amdgcn_mfma_f32_16x16x32_bf16(ah[mt], bh[cg], acc[mt][cg], 0, 0, 0);
        acc[mt][cg] = __builtin_amdgcn_mfma_f32_16x16x32_bf16(al[mt], bh[cg], acc[mt][cg], 0, 0, 0);
        acc[mt][cg] = __builtin_amdgcn_mfma_f32_16x16x32_bf16(ah[mt], bl[cg], acc[mt][cg], 0, 0, 0);
      }
  }

  float* hb = h + (((size_t)b) << 15) * 64;
#pragma unroll
  for (int cg = 0; cg < 4; cg++) {
    int o = cg * 16 + col;
    float bias = ct_b[o];
#pragma unroll
    for (int mt = 0; mt < 4; mt++)
#pragma unroll
      for (int r = 0; r < 4; r++) {
        int mm = mm0 + mt * 16 + q * 4 + r;
        int t = mm * 8 + phi;
        hb[(size_t)t * 64 + o] = acc[mt][cg][r] + bias;
      }
  }
}

// ---------------- conditioning network (tiny) -----------------
__global__ __launch_bounds__(256) void conv5_kernel(const float* __restrict__ c,
                                                    const float* __restrict__ w,
                                                    const float* __restrict__ bias,
                                                    float* __restrict__ cc) {
  int f = blockIdx.x * 256 + threadIdx.x;  // 32768
  int o = f & 63, t = (f >> 6) & 127, b = f >> 13;
  float acc = bias[o];
  for (int kk = 0; kk < 5; kk++) {
    int tt = t + kk - 2;
    if (tt < 0 || tt >= 128) continue;
    const float* cr = c + (b * 128 + tt) * 80;
    const float* wr = w + kk * 80 * 64 + o;
    for (int i = 0; i < 80; i++) acc += cr[i] * wr[i * 64];
  }
  cc[f] = leaky(acc);
}

template <int ADD>
__global__ __launch_bounds__(256) void conv3_kernel(const float* __restrict__ xin,
                                                    const float* __restrict__ w,
                                                    const float* __restrict__ bias,
                                                    const float* __restrict__ addsrc,
                                                    float* __restrict__ out) {
  int f = blockIdx.x * 256 + threadIdx.x;  // 32768
  int o = f & 63, t = (f >> 6) & 127, b = f >> 13;
  float acc = bias[o];
  for (int kk = 0; kk < 3; kk++) {
    int tt = t + kk - 1;
    if (tt < 0 || tt >= 128) continue;
    const float* xr = xin + (b * 128 + tt) * 64;
    const float* wr = w + kk * 64 * 64 + o;
    for (int i = 0; i < 64; i++) acc += xr[i] * wr[i * 64];
  }
  float v = leaky(acc);
  if (ADD) v += addsrc[f];
  out[f] = v;
}

// ---------------- im2col patches for the prediction GEMMs -----------------
__global__ __launch_bounds__(256) void patch_kernel(const float* __restrict__ cc,
                                                    float* __restrict__ A) {
  int f = blockIdx.x * 256 + threadIdx.x;  // 98304
  int k = f % 192, m = f / 192;
  int b = m >> 7, l = m & 127;
  int kk = k >> 6, hh = k & 63;
  int ll = l + kk - 1;
  A[f] = (ll >= 0 && ll < 128) ? cc[((b << 7) + ll) * 64 + hh] : 0.f;
}

__global__ __launch_bounds__(256) void bbgemm_kernel(const float* __restrict__ A,
                                                     const float* __restrict__ w,
                                                     const float* __restrict__ bias,
                                                     float* __restrict__ bb) {
  int f = blockIdx.x * 256 + threadIdx.x;  // 262144
  int n = f & 511, m = f >> 9;
  float acc = bias[n];
  const float* ar = A + m * 192;
  const float* wr = w + n;
  for (int k = 0; k < 192; k++) acc += ar[k] * wr[k * 512];
  bb[f] = acc;
}

// ---------------- W -> Wf (P-ordered fragment layout) via LDS-tiled transpose ------
// Block = (l2, kf, ih, cb32): c0 = cb*32 -> each (k,i) row's 32 c = one 128-B line,
// read entirely by ONE lane (8 consecutive f32x4). No line is shared across lanes
// or blocks -> HBM fetch = exactly one pass of W. LDS rows padded to 34 shorts.
__global__ __launch_bounds__(256) void wfrag_kernel(const float* __restrict__ W,
                                                    unsigned short* __restrict__ Wf) {
  __shared__ unsigned short wl[512 * 34];  // 34816 B, row = kl*16+il
  int tid = threadIdx.x;
  int bid = blockIdx.x;  // 1152 = 12 cb * 6 kf * 4 ih * 4 l2
  int cb = bid % 12;
  int r1 = bid / 12;
  int kf = r1 % 6;
  int r2 = r1 / 6;
  int ih = r2 % 4, l2 = r2 / 4;
  int c0 = cb * 32;
  for (int it = 0; it < 2; it++) {
    int row = it * 256 + tid;  // kl*16 + il
    int kl = row >> 4, il = row & 15;
    int i = ih * 16 + il;
    const float* src = W + (size_t)(kf * 32 + kl) * LWN + l2 * 24576 + i * 384 + c0;
    unsigned short* dst = wl + row * 34;
#pragma unroll
    for (int j8 = 0; j8 < 4; j8++) {
      f32x4 a = *(const f32x4*)(src + j8 * 8);
      f32x4 b2 = *(const f32x4*)(src + j8 * 8 + 4);
      u16x8 v;
      for (int j = 0; j < 4; j++) v[j] = f2bf(a[j]);
      for (int j = 0; j < 4; j++) v[4 + j] = f2bf(b2[j]);
      *(u16x8*)(dst + j8 * 8) = v;
    }
  }
  __syncthreads();
  for (int it = 0; it < 8; it++) {
    int slot = it * 256 + tid;  // cl*64 + ln
    int cl = slot >> 6, ln = slot & 63;
    int q = ln >> 4, col = ln & 15;
    u16x8 v;
#pragma unroll
    for (int j = 0; j < 8; j++) {
      int row = (q * 8 + j) * 16 + col;
      v[j] = wl[row * 34 + cl];
    }
    int nt = l2 * 1536 + (c0 + cl) * 4 + ih;
    *(u16x8*)(Wf + ((size_t)(nt * 6 + kf) * 64 + ln) * 8) = v;
  }
}

__global__ __launch_bounds__(256) void afrag_kernel(const float* __restrict__ A,
                                                    unsigned short* __restrict__ Af) {
  int ft = blockIdx.x * 256 + threadIdx.x;  // 12288
  int lane = ft & 63, fragid = ft >> 6;
  int kf = fragid % 6, mt = fragid / 6;
  int row = lane & 15, q = lane >> 4;
  const float* ar = A + (mt * 16 + row) * 192 + kf * 32 + q * 8;
  u16x8 v;
  for (int j = 0; j < 8; j++) v[j] = f2bf(ar[j]);
  *(u16x8*)(Af + ((size_t)fragid * 64 + lane) * 8) = v;
}

// ---------------- dconv weights -> B-fragment layout (all 4 layers, built once) ----
__global__ __launch_bounds__(256) void dwfrag_kernel(const float* __restrict__ conv_w,
                                                     unsigned short* __restrict__ dwf) {
  int ft = blockIdx.x * 256 + threadIdx.x;  // 6144
  int lane = ft & 63, frag = ft >> 6;       // 96 frags
  int lay = frag / 24, fr = frag % 24;
  int nt = fr / 6, kf = fr % 6;
  int o = nt * 16 + (lane & 15);
  int k0 = kf * 32 + (lane >> 4) * 8;
  u16x8 v;
  for (int j = 0; j < 8; j++) {
    int k = k0 + j, kk = k >> 6, i = k & 63;
    v[j] = f2bf(conv_w[lay * 12288 + kk * 4096 + i * 64 + o]);
  }
  *(u16x8*)(dwf + ((size_t)frag * 64 + lane) * 8) = v;
}

// ---------------- k = A @ W + kern_b, output C[m][P] (P-permuted columns) ----------
__global__ __launch_bounds__(256) void kgemm_kernel(const unsigned short* __restrict__ Af,
                                                    const unsigned short* __restrict__ Wf,
                                                    const float* __restrict__ kern_b,
                                                    unsigned short* __restrict__ kbs) {
  __shared__ unsigned short cl[256 * 68];
  int tid = threadIdx.x;
  int wave = tid >> 6, lane = tid & 63;
  int col = lane & 15, q = lane >> 4;
  int mt0 = blockIdx.y * 16 + wave * 4;
  int nt0 = blockIdx.x * 4;
  f32x4 acc[4][4];
  for (int a = 0; a < 4; a++)
    for (int cg = 0; cg < 4; cg++) acc[a][cg] = (f32x4){0.f, 0.f, 0.f, 0.f};
  const s16x8* ap = (const s16x8*)Af;
  const s16x8* bp = (const s16x8*)Wf;
  for (int kf = 0; kf < 6; kf++) {
    s16x8 av[4], bv[4];
    for (int a = 0; a < 4; a++) av[a] = ap[((mt0 + a) * 6 + kf) * 64 + lane];
    for (int cg = 0; cg < 4; cg++) bv[cg] = bp[((size_t)(nt0 + cg) * 6 + kf) * 64 + lane];
    for (int a = 0; a < 4; a++)
      for (int cg = 0; cg < 4; cg++)
        acc[a][cg] = __builtin_amdgcn_mfma_f32_16x16x32_bf16(av[a], bv[cg], acc[a][cg], 0, 0, 0);
  }
  for (int cg = 0; cg < 4; cg++) {
    float bias = kern_b[perm_n_of_P((nt0 + cg) * 16 + col)];
    for (int a = 0; a < 4; a++) {
      int lr0 = wave * 64 + a * 16 + q * 4;
      for (int r = 0; r < 4; r++)
        cl[(lr0 + r) * 68 + cg * 16 + col] = f2bf(acc[a][cg][r] + bias);
    }
  }
  __syncthreads();
  size_t mbase = (size_t)blockIdx.y * 256;
  int nbase = blockIdx.x * 64;
#pragma unroll
  for (int rep = 0; rep < 8; rep++) {
    int cid = rep * 256 + tid;
    int row = cid >> 3, ch = cid & 7;
    u16x8 vv = *(const u16x8*)(cl + row * 68 + ch * 8);
    *(u16x8*)(kbs + (mbase + row) * LWN + nbase + ch * 8) = vv;
  }
}

// ---------------- dilated conv as MFMA GEMM: M=131072, N=64, K=192 ----------------
__global__ __launch_bounds__(256) void dconv_kernel(const float* __restrict__ h,
                                                    const unsigned short* __restrict__ dwf,
                                                    const float* __restrict__ conv_b,
                                                    unsigned short* __restrict__ xc,
                                                    int lay, int d) {
  int tid = threadIdx.x;
  int w = tid >> 6, lane = tid & 63;
  int col = lane & 15, q = lane >> 4;
  int m0 = blockIdx.x * 256 + w * 64;
  int b = m0 >> 15, t0 = m0 & 32767;
  const float* hb = h + (((size_t)b) << 15) * 64;
  const s16x8* wf = (const s16x8*)(dwf + (size_t)lay * 24 * 512);

  f32x4 acc[4][4];
  for (int mt = 0; mt < 4; mt++)
    for (int cg = 0; cg < 4; cg++) acc[mt][cg] = (f32x4){0.f, 0.f, 0.f, 0.f};

#pragma unroll
  for (int kf = 0; kf < 6; kf++) {
    s16x8 bv[4];
#pragma unroll
    for (int cg = 0; cg < 4; cg++) bv[cg] = wf[(cg * 6 + kf) * 64 + lane];
    int k0 = kf * 32 + q * 8;
    int kk = k0 >> 6, i0 = k0 & 63;
    int dt = (kk - 1) * d;
    s16x8 ah[4], al[4];
#pragma unroll
    for (int mt = 0; mt < 4; mt++) {
      int t = t0 + mt * 16 + col + dt;
      bool oob = ((unsigned)t >= (unsigned)TSZ);
      int tc = oob ? 0 : t;
      f32x8 v = *(const f32x8*)(hb + (size_t)tc * 64 + i0);
#pragma unroll
      for (int j = 0; j < 8; j++) {
        float xv = oob ? 0.f : leaky(v[j]);
        short hi, lo;
        split_trunc(xv, hi, lo);
        ah[mt][j] = hi;
        al[mt][j] = lo;
      }
    }
#pragma unroll
    for (int mt = 0; mt < 4; mt++)
#pragma unroll
      for (int cg = 0; cg < 4; cg++) {
        acc[mt][cg] = __builtin_amdgcn_mfma_f32_16x16x32_bf16(ah[mt], bv[cg], acc[mt][cg], 0, 0, 0);
        acc[mt][cg] = __builtin_amdgcn_mfma_f32_16x16x32_bf16(al[mt], bv[cg], acc[mt][cg], 0, 0, 0);
      }
  }

  unsigned short* xb = xc + (((size_t)b) << 15) * 64;
#pragma unroll
  for (int cg = 0; cg < 4; cg++) {
    int o = cg * 16 + col;
    float bias = conv_b[lay * 64 + o];
#pragma unroll
    for (int mt = 0; mt < 4; mt++)
#pragma unroll
      for (int r = 0; r < 4; r++) {
        int t = t0 + mt * 16 + q * 4 + r;
        xb[(size_t)t * 64 + o] = f2bf(leaky(acc[mt][cg][r] + bias));
      }
  }
}

// ---------------- LVC as per-(b,l) MFMA GEMM: M=256, N=128, K=192 ----------------
// B-frags 16B-contiguous in the P-permuted kb: addr = srow + (o*3+kk)*64 + i0.
__global__ __launch_bounds__(512) void lvc_kernel(const unsigned short* __restrict__ xc,
                                                  const unsigned short* __restrict__ kbs,
                                                  const float* __restrict__ bbv,
                                                  float* __restrict__ h, int lay) {
  int tid = threadIdx.x;
  int l = blockIdx.x & 127, b = blockIdx.x >> 7;
  int w = tid >> 6, lane = tid & 63;
  int wm = w & 3, wn = w >> 2;
  int col = lane & 15, qq = lane >> 4;
  const unsigned short* srow =
      kbs + (size_t)(b * 128 + lay * 32 + (l >> 2)) * LWN + (l & 3) * 24576;
  const unsigned short* xb = xc + (((size_t)b) << 15) * 64;

  f32x4 acc[4][4];
  for (int mt = 0; mt < 4; mt++)
    for (int cg = 0; cg < 4; cg++) acc[mt][cg] = (f32x4){0.f, 0.f, 0.f, 0.f};

  s16x8 av[2][4], bv[2][4];
  const s16x8 zfrag = {0, 0, 0, 0, 0, 0, 0, 0};

#define LOAD_STEP(p, kf)                                                            \
  {                                                                                 \
    int k0 = (kf) * 32 + qq * 8;                                                    \
    int kk = k0 >> 6, i0 = k0 & 63;                                                 \
    _Pragma("unroll") for (int mt = 0; mt < 4; mt++) {                              \
      int s = wm * 64 + mt * 16 + col;                                              \
      int nr = 3 * s + kk - 255;                                                    \
      int n = nr < 0 ? -nr : (nr >= 258 ? 514 - nr : nr);                           \
      int t = l * 256 + n - 1;                                                      \
      bool oob = ((unsigned)t >= (unsigned)TSZ);                                    \
      int tc = oob ? 0 : t;                                                         \
      s16x8 v = *(const s16x8*)(xb + (size_t)tc * 64 + i0);                         \
      av[p][mt] = oob ? zfrag : v;                                                  \
    }                                                                               \
    _Pragma("unroll") for (int cg = 0; cg < 4; cg++) {                              \
      int nt = 2 * wn + (cg & 1) + ((cg >> 1) << 2);                                \
      int o = nt * 16 + col;                                                        \
      bv[p][cg] = *(const s16x8*)(srow + (o * 3 + kk) * 64 + i0);                   \
    }                                                                               \
  }

  LOAD_STEP(0, 0)
#pragma unroll
  for (int kf = 0; kf < 6; kf++) {
    int cur = kf & 1, nxt = cur ^ 1;
    if (kf < 5) LOAD_STEP(nxt, kf + 1)
#pragma unroll
    for (int mt = 0; mt < 4; mt++)
#pragma unroll
      for (int cg = 0; cg < 4; cg++)
        acc[mt][cg] =
            __builtin_amdgcn_mfma_f32_16x16x32_bf16(av[cur][mt], bv[cur][cg], acc[mt][cg], 0, 0, 0);
  }
#undef LOAD_STEP

  // epilogue: bias + sigmoid*tanh gate + h residual update
  int lq = l >> 2, l2 = l & 3;
  const float* bb0 = bbv + (size_t)(b * 128 + lay * 32 + lq) * 512 + l2 * 128;
  float* hb = h + ((((size_t)b) << 15) + l * 256) * 64;
#pragma unroll
  for (int mt = 0; mt < 4; mt++) {
#pragma unroll
    for (int p = 0; p < 2; p++) {
      int o = (2 * wn + p) * 16 + col;
      float b0 = bb0[o], b1 = bb0[o + 64];
#pragma unroll
      for (int r = 0; r < 4; r++) {
        int s = wm * 64 + mt * 16 + qq * 4 + r;
        float a0 = acc[mt][p][r] + b0;
        float a1 = acc[mt][p + 2][r] + b1;
        float sg = 1.f / (1.f + __expf(-a0));
        float ex = __expf(2.f * a1);
        float th = 1.f - 2.f / (ex + 1.f);
        hb[(size_t)s * 64 + o] += sg * th;
      }
    }
  }
}

extern "C" void kernel_launch(void* const* d_in, const int* in_sizes, int n_in,
                              void* d_out, int out_size, void* d_ws, size_t ws_size,
                              hipStream_t stream) {
  (void)in_sizes; (void)n_in; (void)out_size; (void)ws_size;
  const float* x      = (const float*)d_in[0];
  const float* c      = (const float*)d_in[1];
  const float* ct_w   = (const float*)d_in[2];
  const float* ct_b   = (const float*)d_in[3];
  const float* conv_w = (const float*)d_in[4];
  const float* conv_b = (const float*)d_in[5];
  const float* inp_w  = (const float*)d_in[6];
  const float* inp_b  = (const float*)d_in[7];
  const float* res_w1 = (const float*)d_in[8];
  const float* res_b1 = (const float*)d_in[9];
  const float* res_w2 = (const float*)d_in[10];
  const float* res_b2 = (const float*)d_in[11];
  const float* kern_w = (const float*)d_in[12];
  const float* kern_b = (const float*)d_in[13];
  const float* bias_w = (const float*)d_in[14];
  const float* bias_b = (const float*)d_in[15];

  float* h = (float*)d_out;  // h lives in d_out (fully written by ctm_kernel)
  char* ws = (char*)d_ws;
  // region [0, 37748736): Wf during GEMM phase, then reused as bf16 xc in layer phase
  unsigned short* Wf = (unsigned short*)(ws);
  unsigned short* xc = (unsigned short*)(ws);
  unsigned short* kb = (unsigned short*)(ws + 37748736);   // 100663296 B ([m][P] bf16)
  float* A           = (float*)(ws + 138412032);           // 393216 B
  unsigned short* Af = (unsigned short*)(ws + 138805248);  // 196608 B
  float* cc          = (float*)(ws + 139001856);           // 131072 B
  float* t1          = (float*)(ws + 139132928);           // 131072 B
  float* bbv         = (float*)(ws + 139264000);           // 1048576 B
  unsigned short* dwf = (unsigned short*)(ws + 140312576); // 98304 B
  // ctwf (262144 B) overlaps A/Af region: dead before patch_kernel writes A.
  unsigned short* ctwf = (unsigned short*)(ws + 138412032);

  ctwfrag_kernel<<<dim3(32), dim3(256), 0, stream>>>(ct_w, ctwf);
  ctm_kernel<<<dim3(512), dim3(256), 0, stream>>>(x, ctwf, ct_b, h);
  conv5_kernel<<<dim3(128), dim3(256), 0, stream>>>(c, inp_w, inp_b, cc);
  for (int j = 0; j < 3; j++) {
    conv3_kernel<0><<<dim3(128), dim3(256), 0, stream>>>(cc, res_w1 + j * 12288, res_b1 + j * 64,
                                                         (const float*)nullptr, t1);
    conv3_kernel<1><<<dim3(128), dim3(256), 0, stream>>>(t1, res_w2 + j * 12288, res_b2 + j * 64,
                                                         cc, cc);
  }
  patch_kernel<<<dim3(384), dim3(256), 0, stream>>>(cc, A);
  bbgemm_kernel<<<dim3(1024), dim3(256), 0, stream>>>(A, bias_w, bias_b, bbv);
  wfrag_kernel<<<dim3(1152), dim3(256), 0, stream>>>(kern_w, Wf);
  afrag_kernel<<<dim3(48), dim3(256), 0, stream>>>(A, Af);
  kgemm_kernel<<<dim3(1536, 2), dim3(256), 0, stream>>>(Af, Wf, kern_b, kb);
  dwfrag_kernel<<<dim3(24), dim3(256), 0, stream>>>(conv_w, dwf);

  const int dil[4] = {1, 3, 9, 27};
  for (int lay = 0; lay < 4; lay++) {
    dconv_kernel<<<dim3(512), dim3(256), 0, stream>>>(h, dwf, conv_b, xc, lay, dil[lay]);
    lvc_kernel<<<dim3(512), dim3(512), 0, stream>>>(xc, kb, bbv, h, lay);
  }
}